// Round 7
// baseline (204.672 us; speedup 1.0000x reference)
//
#include <hip/hip_runtime.h>

// ---------------------------------------------------------------------------
// Problem constants
#define BQ 2048
#define NS 32768
#define DIM 256
#define NROWS (NS + BQ)

// Fast-path (MFMA) tiling: block = 256q x 128s, 4 waves, wave = 64q x 128s.
// R17: X (wave-private rows) in REGISTERS (4 f16x8 loads/stage); only S is
// LDS-staged (triple-buffered, 24 KB -> 3 blocks/CU).
// R18: R17 failed with a provable race: the compiler hoisted the prologue-
// adjacent A-register loads above issueS(0/1) in the vmcnt FIFO, so
// vmcnt(6) drained A-loads instead of S0 -> MFMA(0) read unstaged LDS.
// Fix: compiler fences pin VMEM issue order to
//   [S0,S1, A(0)] [S2, A(1)] [S3, A(2)] ...
// FIFO proof: S(s+1) is older than A(s); the compiler MUST wait for A(s)
// before MFMA(s) (register dep), which drains S(s+1) before barrier(s+1).
// vmcnt(6)/vmcnt(4) immediates cover prologue/tail.
#define BMQ 256                // queries per block
#define BNS 128                // supports per block
#define BK 32                  // K per stage
#define NST (DIM / BK)         // 8 pipeline stages
#define GY (NS / BNS)          // 256 chunks per query
#define GX (BQ / BMQ)          // 8 query tiles
// Certification: score = s2 - 2*(xh . sh), RTN f16. EPS = 0.08 ~ 8 sigma of
// per-pair error (validated: absmax 0 at R9-R16). Flagged queries get an
// exact candidate-chunk rescan inline (chunk c can hold the exact argmin
// only if pv1[c] <= qbest + EPS).
#define EPS 0.08f

typedef _Float16 f16;
typedef _Float16 f16x4 __attribute__((ext_vector_type(4)));
typedef _Float16 f16x8 __attribute__((ext_vector_type(8)));
typedef float    f32x4 __attribute__((ext_vector_type(4)));

#define MEMFENCE asm volatile("" ::: "memory")

// ---------------------------------------------------------------------------
// global->LDS DMA, 16B/lane; LDS dest = wave-uniform base + lane*16.
// Per-lane source address carries the XOR swizzle (R7-verified: 0 conflicts).
// ---------------------------------------------------------------------------
__device__ __forceinline__ void gload16(const f16* g, f16* l) {
    __builtin_amdgcn_global_load_lds(
        (const __attribute__((address_space(1))) unsigned int*)g,
        (__attribute__((address_space(3))) unsigned int*)l, 16, 0, 0);
}

// Swizzled fragment pointer: rows of 32 f16 (64 B), cell q stored at
// q ^ ((row>>1)&3).  (S-side only since R17.)
__device__ __forceinline__ const f16x8* fragp(const f16* base, int row, int q) {
    return (const f16x8*)(base + row * 32 + ((q ^ ((row >> 1) & 3)) << 3));
}

// ---------------------------------------------------------------------------
// Kernel 1 (R4-proven): x -> f16 xh row-major, sup -> f16 sh row-major, s2
// exact fp32. One wave per row; contiguous 512B/wave writes.
// ---------------------------------------------------------------------------
__global__ __launch_bounds__(256) void convert_kernel(
    const float* __restrict__ x, const float* __restrict__ sup,
    f16* __restrict__ xh, f16* __restrict__ sh, float* __restrict__ s2) {
    const int wave = threadIdx.x >> 6, lane = threadIdx.x & 63;
    const int row = blockIdx.x * 4 + wave;
    if (row < NS) {
        float4 v = ((const float4*)(sup + (size_t)row * DIM))[lane];
        f16x4 hi;
        hi[0] = (f16)v.x; hi[1] = (f16)v.y; hi[2] = (f16)v.z; hi[3] = (f16)v.w;
        *(f16x4*)(sh + (size_t)row * DIM + lane * 4) = hi;
        float sum = v.x * v.x + v.y * v.y + v.z * v.z + v.w * v.w;
#pragma unroll
        for (int off = 32; off > 0; off >>= 1) sum += __shfl_xor(sum, off);
        if (lane == 0) s2[row] = sum;
    } else {
        const int q = row - NS;
        float4 v = ((const float4*)(x + (size_t)q * DIM))[lane];
        f16x4 hi;
        hi[0] = (f16)v.x; hi[1] = (f16)v.y; hi[2] = (f16)v.z; hi[3] = (f16)v.w;
        *(f16x4*)(xh + (size_t)q * DIM + lane * 4) = hi;
    }
}

// ---------------------------------------------------------------------------
// Kernel 2 (R18): f16 MFMA GEMM + top-2 argmin. 256x128 block tile.
// - A-frags: direct global->VGPR f16x8 loads (X rows wave-private; value is
//   identical to the old de-swizzled LDS read: xh[row][s*32 + quad*8]).
// - S: triple-buffered LDS (24 KB), 2 gload16/wave/stage, swizzled source.
// - VMEM order pinned by MEMFENCE: [S0,S1,A(0)] [S(s+2),A(s+1)] per region.
//   Correctness: S(s+1) older than A(s) => compiler's mandatory A(s)-wait
//   before MFMA(s) drains S(s+1) (FIFO) before barrier(s+1). vmcnt(6)
//   drains S0 at s=0; vmcnt(4) drains S7 at s=7.
// - R13 bijective XCD swizzle kept (FETCH 66.6->12.4 MB verified).
// ---------------------------------------------------------------------------
__global__ __launch_bounds__(256, 3) void knn_mfma(
    const f16* __restrict__ xh, const f16* __restrict__ sh,
    const float* __restrict__ s2g,
    float* __restrict__ pv1, float* __restrict__ pv2, int* __restrict__ pi1) {
    __shared__ f16 T[3][BNS * 32];       // S triple-buffer, 24 KB

    const int tid  = threadIdx.x;
    const int lane = tid & 63, wid = tid >> 6;
    const int l16  = lane & 15, quad = lane >> 4;

    // R13 swizzle: id = y*GX+x (x fastest in dispatch order); id%8 -> XCD.
    const int id   = blockIdx.y * GX + blockIdx.x;
    const int xcd  = id & 7;
    const int slot = id >> 3;                 // 0..(GX*GY/8 - 1)
    const int gx   = slot & (GX - 1);         // q-tile, fastest per XCD
    const int gy   = xcd * (GY / 8) + (slot >> 3);  // sh slice, XCD-local
    const int m0   = gx * BMQ;
    const int n0   = gy * BNS;

    // S-DMA per-lane swizzled source offset (one call = 16 rows x 32 f16)
    const int rl = lane >> 2;
    const int qs = (lane & 3) ^ ((rl >> 1) & 3);
    const size_t srcoff = (size_t)rl * DIM + qs * 8;
    const f16* ps0 = sh + (size_t)(n0 + wid * 32) * DIM + srcoff;
    const f16* ps1 = ps0 + (size_t)16 * DIM;
    const int dS = wid * 1024;           // f16 offset of S row 32w in buffer

    // A-frag base: row m0 + wid*64 + l16, k-offset quad*8 (16B aligned)
    const f16* pA = xh + (size_t)(m0 + wid * 64 + l16) * DIM + quad * 8;

    f32x4 acc[4][8];
#pragma unroll
    for (int fi = 0; fi < 4; ++fi)
#pragma unroll
        for (int fj = 0; fj < 8; ++fj) acc[fi][fj] = (f32x4){0.f, 0.f, 0.f, 0.f};

    auto issueS = [&](int s) {
        f16* bs = &T[s % 3][dS];
        const int k0 = s * BK;
        gload16(ps0 + k0, bs);
        gload16(ps1 + k0, bs + 512);
    };

    // prologue: 2 S-stages in flight, FENCED so nothing hoists above them
    issueS(0);
    issueS(1);
    MEMFENCE;                 // R18: pin S0,S1 as the oldest vmcnt entries

#pragma unroll
    for (int s = 0; s < NST; ++s) {
        // A regs for this stage. MEMFENCE pins them AFTER issueS(s+1) /
        // prologue in the vmcnt FIFO; the waitcnt-asm below pins the tail.
        MEMFENCE;
        f16x8 A0 = *(const f16x8*)(pA +  0 * DIM + s * BK);
        f16x8 A1 = *(const f16x8*)(pA + 16 * DIM + s * BK);
        f16x8 A2 = *(const f16x8*)(pA + 32 * DIM + s * BK);
        f16x8 A3 = *(const f16x8*)(pA + 48 * DIM + s * BK);
        if (s < NST - 1)
            asm volatile("s_waitcnt vmcnt(6)\n\ts_barrier" ::: "memory");
        else
            asm volatile("s_waitcnt vmcnt(4)\n\ts_barrier" ::: "memory");
        if (s + 2 < NST) issueS(s + 2);

        const f16* TS = &T[s % 3][0];
#pragma unroll
        for (int fj = 0; fj < 8; ++fj) {
            f16x8 B = *fragp(TS, fj * 16 + l16, quad);
            acc[0][fj] = __builtin_amdgcn_mfma_f32_16x16x32_f16(A0, B, acc[0][fj], 0, 0, 0);
            acc[1][fj] = __builtin_amdgcn_mfma_f32_16x16x32_f16(A1, B, acc[1][fj], 0, 0, 0);
            acc[2][fj] = __builtin_amdgcn_mfma_f32_16x16x32_f16(A2, B, acc[2][fj], 0, 0, 0);
            acc[3][fj] = __builtin_amdgcn_mfma_f32_16x16x32_f16(A3, B, acc[3][fj], 0, 0, 0);
        }
    }

    // epilogue: per-slot top-2 over 8 cols, 16-lane merge, write partials
    float s2v[8];
#pragma unroll
    for (int fj = 0; fj < 8; ++fj) s2v[fj] = s2g[n0 + fj * 16 + l16];
#pragma unroll
    for (int fi = 0; fi < 4; ++fi)
#pragma unroll
        for (int rg = 0; rg < 4; ++rg) {
            float bv1 = 3.4e38f, bv2 = 3.4e38f; int bi = 0;
#pragma unroll
            for (int fj = 0; fj < 8; ++fj) {
                float s = fmaf(-2.f, acc[fi][fj][rg], s2v[fj]);
                bv2 = fminf(bv2, fmaxf(bv1, s));
                bi  = (s < bv1) ? (n0 + fj * 16 + l16) : bi;
                bv1 = fminf(bv1, s);
            }
#pragma unroll
            for (int m = 1; m < 16; m <<= 1) {
                float ov1 = __shfl_xor(bv1, m);
                float ov2 = __shfl_xor(bv2, m);
                int   oi  = __shfl_xor(bi, m);
                float nb2 = fminf(fminf(bv2, ov2), fmaxf(bv1, ov1));
                bi  = (ov1 < bv1) ? oi : bi;
                bv1 = fminf(bv1, ov1);
                bv2 = nb2;
            }
            if (l16 == 0) {
                const int row = m0 + wid * 64 + fi * 16 + quad * 4 + rg;
                pv1[(size_t)row * GY + gy] = bv1;
                pv2[(size_t)row * GY + gy] = bv2;
                pi1[(size_t)row * GY + gy] = bi;
            }
        }
}

// ---------------------------------------------------------------------------
// Kernel 3 (R15-proven): FUSED finalize. One block per query, 128 threads:
//   phase 1 (wave 0): merge GY chunk-top2s -> (bv1, bv2, bi).
//   phase 2 (uniform branch): if bv2-bv1 <= EPS, exact fp32 rescan of
//     candidate chunks (pv1[c] <= bv1+EPS) inline (ascending-index
//     tie-break).
//   phase 3: label lookup + one-hot write.
// ---------------------------------------------------------------------------
__global__ __launch_bounds__(128) void finalize_fused(
    const float* __restrict__ pv1, const float* __restrict__ pv2,
    const int* __restrict__ pi1, const float* __restrict__ x,
    const float* __restrict__ sup, const float* __restrict__ s2,
    const int* __restrict__ labels, const int* __restrict__ ncp,
    int* __restrict__ out) {
    const int q = blockIdx.x, tid = threadIdx.x;
    const int lane = tid & 63, w = tid >> 6;      // 2 waves
    __shared__ float s_b1, s_b2;
    __shared__ int   s_bi;
    __shared__ float wv[2];
    __shared__ int   wi[2];
    __shared__ int   s_lbl;

    // phase 1: wave 0 merges the GY=256 chunk top-2 partials
    if (w == 0) {
        float bv1 = 3.4e38f, bv2 = 3.4e38f; int bi = 0;
        for (int t = lane; t < GY; t += 64) {
            float ov1 = pv1[(size_t)q * GY + t];
            float ov2 = pv2[(size_t)q * GY + t];
            int   oi  = pi1[(size_t)q * GY + t];
            float nb2 = fminf(fminf(bv2, ov2), fmaxf(bv1, ov1));
            bi  = (ov1 < bv1) ? oi : bi;
            bv1 = fminf(bv1, ov1);
            bv2 = nb2;
        }
#pragma unroll
        for (int m = 1; m < 64; m <<= 1) {
            float ov1 = __shfl_xor(bv1, m);
            float ov2 = __shfl_xor(bv2, m);
            int   oi  = __shfl_xor(bi, m);
            float nb2 = fminf(fminf(bv2, ov2), fmaxf(bv1, ov1));
            bi  = (ov1 < bv1) ? oi : bi;
            bv1 = fminf(bv1, ov1);
            bv2 = nb2;
        }
        if (lane == 0) { s_b1 = bv1; s_b2 = bv2; s_bi = bi; }
    }
    __syncthreads();
    int bi = s_bi;

    // phase 2: exact rescan for uncertified queries (block-uniform branch)
    if (s_b2 - s_b1 <= EPS) {
        const float qb = s_b1;
        const float4 xv = ((const float4*)(x + (size_t)q * DIM))[lane];
        float best = 3.4e38f; int bn = 0x7fffffff;
        for (int c = 0; c < GY; ++c) {
            if (pv1[(size_t)q * GY + c] > qb + EPS) continue;  // uniform skip
            const int base = c * BNS + w * 64;     // wave w: rows base..base+63
#pragma unroll 4
            for (int r = 0; r < 64; ++r) {
                const int n = base + r;
                float4 sv = ((const float4*)(sup + (size_t)n * DIM))[lane];
                float d = fmaf(sv.x, xv.x,
                          fmaf(sv.y, xv.y,
                          fmaf(sv.z, xv.z, sv.w * xv.w)));
#pragma unroll
                for (int m = 32; m > 0; m >>= 1) d += __shfl_xor(d, m);
                float sc = s2[n] - 2.f * d;
                if (sc < best) { best = sc; bn = n; }   // ascending n, strict <
            }
        }
        if (lane == 0) { wv[w] = best; wi[w] = bn; }
        __syncthreads();
        if (tid == 0) {
            float bv = wv[0]; int bx = wi[0];
            if (wv[1] < bv || (wv[1] == bv && wi[1] < bx)) { bx = wi[1]; }
            s_bi = bx;
        }
        __syncthreads();
        bi = s_bi;
    }

    // phase 3: label + one-hot
    if (tid == 0) {
        bool is64 = true;
        for (int i = 1; i < 128; i += 2)
            if (labels[i] != 0) { is64 = false; break; }
        s_lbl = is64 ? labels[2 * bi] : labels[bi];
    }
    __syncthreads();
    const int nc = ncp[0], lbl = s_lbl;
    for (int c = tid; c < nc; c += 128)
        out[q * nc + c] = (c == lbl) ? 1 : 0;
}

// ===========================================================================
// Slow path (ws too small): proven R3 fp32 kernels.
// ===========================================================================
#define SBM 128
#define SBN 128
#define SBK 16
#define SNT 4
#define SGY (NS / (SBN * SNT))
#define SLDT (SBM + 4)

__global__ __launch_bounds__(256) void s2_kernel(const float* __restrict__ s,
                                                 float* __restrict__ s2) {
    int wave = threadIdx.x >> 6, lane = threadIdx.x & 63;
    int row = blockIdx.x * 4 + wave;
    const float4* p = (const float4*)(s + (size_t)row * DIM);
    float4 v = p[lane];
    float sum = v.x * v.x + v.y * v.y + v.z * v.z + v.w * v.w;
#pragma unroll
    for (int off = 32; off > 0; off >>= 1) sum += __shfl_xor(sum, off);
    if (lane == 0) s2[row] = sum;
}

__global__ __launch_bounds__(256) void knn_f32(const float* __restrict__ x,
                                               const float* __restrict__ sup,
                                               const float* __restrict__ s2g,
                                               float* __restrict__ pvals,
                                               int* __restrict__ pidx) {
    __shared__ float Xs[SBK][SLDT];
    __shared__ float Bs[SBK][SLDT];
    const int tid = threadIdx.x;
    const int tx = tid & 15, ty = tid >> 4;
    const int m0 = blockIdx.x * SBM, by = blockIdx.y;
    const int srow = tid >> 2, skq = (tid & 3) * 4;
    float rmin[8]; int ridx[8];
#pragma unroll
    for (int i = 0; i < 8; ++i) { rmin[i] = 3.4e38f; ridx[i] = 0x7fffffff; }
    const float* xr0 = x + (size_t)(m0 + srow) * DIM + skq;
    const float* xr1 = x + (size_t)(m0 + 64 + srow) * DIM + skq;
    for (int nt = 0; nt < SNT; ++nt) {
        const int n0 = (by * SNT + nt) * SBN;
        const float* sr0 = sup + (size_t)(n0 + srow) * DIM + skq;
        const float* sr1 = sup + (size_t)(n0 + 64 + srow) * DIM + skq;
        float acc[8][8];
#pragma unroll
        for (int i = 0; i < 8; ++i)
#pragma unroll
            for (int j = 0; j < 8; ++j) acc[i][j] = 0.0f;
        for (int kt = 0; kt < DIM / SBK; ++kt) {
            const int k0 = kt * SBK;
            float4 xv0 = *(const float4*)(xr0 + k0);
            float4 xv1 = *(const float4*)(xr1 + k0);
            float4 sv0 = *(const float4*)(sr0 + k0);
            float4 sv1 = *(const float4*)(sr1 + k0);
            __syncthreads();
            Xs[skq + 0][srow] = xv0.x; Xs[skq + 1][srow] = xv0.y;
            Xs[skq + 2][srow] = xv0.z; Xs[skq + 3][srow] = xv0.w;
            Xs[skq + 0][64 + srow] = xv1.x; Xs[skq + 1][64 + srow] = xv1.y;
            Xs[skq + 2][64 + srow] = xv1.z; Xs[skq + 3][64 + srow] = xv1.w;
            Bs[skq + 0][srow] = sv0.x; Bs[skq + 1][srow] = sv0.y;
            Bs[skq + 2][srow] = sv0.z; Bs[skq + 3][srow] = sv0.w;
            Bs[skq + 0][64 + srow] = sv1.x; Bs[skq + 1][64 + srow] = sv1.y;
            Bs[skq + 2][64 + srow] = sv1.z; Bs[skq + 3][64 + srow] = sv1.w;
            __syncthreads();
#pragma unroll
            for (int k = 0; k < SBK; ++k) {
                float4 a0 = *(const float4*)&Xs[k][ty * 4];
                float4 a1 = *(const float4*)&Xs[k][64 + ty * 4];
                float4 b0 = *(const float4*)&Bs[k][tx * 4];
                float4 b1 = *(const float4*)&Bs[k][64 + tx * 4];
                float a[8] = {a0.x, a0.y, a0.z, a0.w, a1.x, a1.y, a1.z, a1.w};
                float b[8] = {b0.x, b0.y, b0.z, b0.w, b1.x, b1.y, b1.z, b1.w};
#pragma unroll
                for (int i = 0; i < 8; ++i)
#pragma unroll
                    for (int j = 0; j < 8; ++j)
                        acc[i][j] = fmaf(a[i], b[j], acc[i][j]);
            }
        }
        const int nb0 = n0 + tx * 4, nb1 = n0 + 64 + tx * 4;
        float4 s20 = *(const float4*)(s2g + nb0);
        float4 s21 = *(const float4*)(s2g + nb1);
        float s2a[8] = {s20.x, s20.y, s20.z, s20.w, s21.x, s21.y, s21.z, s21.w};
        int nca[8] = {nb0, nb0 + 1, nb0 + 2, nb0 + 3, nb1, nb1 + 1, nb1 + 2, nb1 + 3};
#pragma unroll
        for (int i = 0; i < 8; ++i)
#pragma unroll
            for (int j = 0; j < 8; ++j) {
                float sc = fmaf(-2.0f, acc[i][j], s2a[j]);
                if (sc < rmin[i] || (sc == rmin[i] && nca[j] < ridx[i])) {
                    rmin[i] = sc; ridx[i] = nca[j];
                }
            }
    }
    __syncthreads();
    float* redv = (float*)Xs;
    int* redi = (int*)Bs;
#pragma unroll
    for (int i = 0; i < 8; ++i) {
        int mrow = (i < 4) ? (ty * 4 + i) : (64 + ty * 4 + (i - 4));
        redv[mrow * 16 + tx] = rmin[i];
        redi[mrow * 16 + tx] = ridx[i];
    }
    __syncthreads();
    if (tid < SBM) {
        float best = redv[tid * 16];
        int bi = redi[tid * 16];
#pragma unroll
        for (int t = 1; t < 16; ++t) {
            float v = redv[tid * 16 + t];
            int ix = redi[tid * 16 + t];
            if (v < best || (v == best && ix < bi)) { best = v; bi = ix; }
        }
        pvals[(size_t)(m0 + tid) * SGY + by] = best;
        pidx[(size_t)(m0 + tid) * SGY + by] = bi;
    }
}

__global__ __launch_bounds__(64) void finalize_f32(const float* __restrict__ pvals,
                                                   const int* __restrict__ pidx,
                                                   const int* __restrict__ labels,
                                                   const int* __restrict__ ncp,
                                                   int* __restrict__ out) {
    const int b = blockIdx.x, lane = threadIdx.x;
    float v = pvals[(size_t)b * SGY + lane];
    int ix = pidx[(size_t)b * SGY + lane];
#pragma unroll
    for (int off = 32; off > 0; off >>= 1) {
        float ov = __shfl_xor(v, off);
        int oi = __shfl_xor(ix, off);
        if (ov < v || (ov == v && oi < ix)) { v = ov; ix = oi; }
    }
    bool is64 = true;
    for (int i = 1; i < 128; i += 2)
        if (labels[i] != 0) { is64 = false; break; }
    const int lbl = is64 ? labels[2 * ix] : labels[ix];
    const int nc = ncp[0];
    for (int c = lane; c < nc; c += 64)
        out[b * nc + c] = (c == lbl) ? 1 : 0;
}

// ---------------------------------------------------------------------------
extern "C" void kernel_launch(void* const* d_in, const int* in_sizes, int n_in,
                              void* d_out, int out_size, void* d_ws, size_t ws_size,
                              hipStream_t stream) {
    const float* x      = (const float*)d_in[0];
    const float* sup    = (const float*)d_in[1];
    const int*   labels = (const int*)d_in[2];
    const int*   ncp    = (const int*)d_in[3];
    int* out = (int*)d_out;

    // fast-path workspace layout (~23.4 MB)
    char* p = (char*)d_ws;
    float* s2      = (float*)p;           p += (size_t)NS * 4;
    float* pv1     = (float*)p;           p += (size_t)BQ * GY * 4;
    float* pv2     = (float*)p;           p += (size_t)BQ * GY * 4;
    int*   pi1     = (int*)p;             p += (size_t)BQ * GY * 4;
    f16*   xh      = (f16*)p;             p += (size_t)BQ * DIM * 2;   // row-major
    f16*   sh      = (f16*)p;             p += (size_t)NS * DIM * 2;   // row-major
    const size_t need = (size_t)(p - (char*)d_ws);

    if (ws_size >= need) {
        convert_kernel<<<NROWS / 4, 256, 0, stream>>>(x, sup, xh, sh, s2);
        dim3 grid(GX, GY);
        knn_mfma<<<grid, 256, 0, stream>>>(xh, sh, s2, pv1, pv2, pi1);
        finalize_fused<<<BQ, 128, 0, stream>>>(pv1, pv2, pi1, x, sup, s2,
                                               labels, ncp, out);
    } else {
        // slow path: proven fp32 pipeline (R3)
        float* ss2   = (float*)d_ws;
        float* pvals = ss2 + NS;
        int*   pidx  = (int*)(pvals + (size_t)BQ * SGY);
        s2_kernel<<<NS / 4, 256, 0, stream>>>(sup, ss2);
        dim3 sgrid(BQ / SBM, SGY);
        knn_f32<<<sgrid, 256, 0, stream>>>(x, sup, ss2, pvals, pidx);
        finalize_f32<<<BQ, 64, 0, stream>>>(pvals, pidx, labels, ncp, out);
    }
}

// Round 9
// 187.188 us; speedup vs baseline: 1.0934x; 1.0934x over previous
//
#include <hip/hip_runtime.h>

// ---------------------------------------------------------------------------
// Problem constants
#define BQ 2048
#define NS 32768
#define DIM 256
#define NROWS (NS + BQ)

// R19: block = 128q x 128s, 4 waves, wave = 32q x 128s. acc[2][8] = 64 VGPR
// + A-frags 8 + misc ~ 115 total -> fits 128 (4 waves/SIMD possible), and
// launch_bounds(256,3) cap 168 GUARANTEES no spill. R18's lesson: the 64q
// wave (acc 128) + min_waves=3 (cap 168) spilled ~190 VGPRs to scratch --
// FETCH 12.5->55 MB, WRITE 10.8->85 MB, MfmaUtil 14%, 96 us.
// X stays in REGISTERS (2 f16x8 loads/stage, wave-private rows); S is LDS
// triple-buffered (24 KB).
#define BMQ 128                // queries per block
#define BNS 128                // supports per block
#define BK 32                  // K per stage
#define NST (DIM / BK)         // 8 pipeline stages
#define GY (NS / BNS)          // 256 chunks per query
#define GX (BQ / BMQ)          // 16 query tiles
// Certification: score = s2 - 2*(xh . sh), RTN f16. EPS = 0.08 ~ 8 sigma of
// per-pair error (validated: absmax 0 at R9-R16, R18). Flagged queries get
// an exact candidate-chunk rescan inline (chunk c can hold the exact argmin
// only if pv1[c] <= qbest + EPS).
#define EPS 0.08f

typedef _Float16 f16;
typedef _Float16 f16x4 __attribute__((ext_vector_type(4)));
typedef _Float16 f16x8 __attribute__((ext_vector_type(8)));
typedef float    f32x4 __attribute__((ext_vector_type(4)));

#define MEMFENCE asm volatile("" ::: "memory")

// ---------------------------------------------------------------------------
// global->LDS DMA, 16B/lane; LDS dest = wave-uniform base + lane*16.
// Per-lane source address carries the XOR swizzle (R7-verified: 0 conflicts).
// ---------------------------------------------------------------------------
__device__ __forceinline__ void gload16(const f16* g, f16* l) {
    __builtin_amdgcn_global_load_lds(
        (const __attribute__((address_space(1))) unsigned int*)g,
        (__attribute__((address_space(3))) unsigned int*)l, 16, 0, 0);
}

// Swizzled fragment pointer: rows of 32 f16 (64 B), cell q stored at
// q ^ ((row>>1)&3).  (S-side only since R17.)
__device__ __forceinline__ const f16x8* fragp(const f16* base, int row, int q) {
    return (const f16x8*)(base + row * 32 + ((q ^ ((row >> 1) & 3)) << 3));
}

// ---------------------------------------------------------------------------
// Kernel 1 (R4-proven): x -> f16 xh row-major, sup -> f16 sh row-major, s2
// exact fp32. One wave per row; contiguous 512B/wave writes.
// ---------------------------------------------------------------------------
__global__ __launch_bounds__(256) void convert_kernel(
    const float* __restrict__ x, const float* __restrict__ sup,
    f16* __restrict__ xh, f16* __restrict__ sh, float* __restrict__ s2) {
    const int wave = threadIdx.x >> 6, lane = threadIdx.x & 63;
    const int row = blockIdx.x * 4 + wave;
    if (row < NS) {
        float4 v = ((const float4*)(sup + (size_t)row * DIM))[lane];
        f16x4 hi;
        hi[0] = (f16)v.x; hi[1] = (f16)v.y; hi[2] = (f16)v.z; hi[3] = (f16)v.w;
        *(f16x4*)(sh + (size_t)row * DIM + lane * 4) = hi;
        float sum = v.x * v.x + v.y * v.y + v.z * v.z + v.w * v.w;
#pragma unroll
        for (int off = 32; off > 0; off >>= 1) sum += __shfl_xor(sum, off);
        if (lane == 0) s2[row] = sum;
    } else {
        const int q = row - NS;
        float4 v = ((const float4*)(x + (size_t)q * DIM))[lane];
        f16x4 hi;
        hi[0] = (f16)v.x; hi[1] = (f16)v.y; hi[2] = (f16)v.z; hi[3] = (f16)v.w;
        *(f16x4*)(xh + (size_t)q * DIM + lane * 4) = hi;
    }
}

// ---------------------------------------------------------------------------
// Kernel 2 (R19): f16 MFMA GEMM + top-2 argmin. 128x128 block tile,
// wave = 32q x 128s.
// - A-frags: 2 direct global->VGPR f16x8 loads/stage (X rows wave-private).
// - S: triple-buffered LDS (24 KB), 2 gload16/wave/stage, swizzled source.
// - VMEM order pinned by MEMFENCE (R18-proven): [S0,S1] [A(0)] [S2,A(1)]...
//   At the stage-s wait: FIFO = S(s):2, S(s+1):2, A(s):2 -> vmcnt(4) drains
//   exactly S(s); last stage FIFO = S7:2, A7:2 -> vmcnt(2).
// - R13 bijective XCD swizzle (GX=16: 8 XCDs x 512 slots, gy = slot>>4).
// ---------------------------------------------------------------------------
__global__ __launch_bounds__(256, 3) void knn_mfma(
    const f16* __restrict__ xh, const f16* __restrict__ sh,
    const float* __restrict__ s2g,
    float* __restrict__ pv1, float* __restrict__ pv2, int* __restrict__ pi1) {
    __shared__ f16 T[3][BNS * 32];       // S triple-buffer, 24 KB

    const int tid  = threadIdx.x;
    const int lane = tid & 63, wid = tid >> 6;
    const int l16  = lane & 15, quad = lane >> 4;

    // R13 swizzle: id = y*GX+x; id%8 -> XCD; bijective (4096 = 8*512).
    const int id   = blockIdx.y * GX + blockIdx.x;
    const int xcd  = id & 7;
    const int slot = id >> 3;                 // 0..511
    const int gx   = slot & (GX - 1);         // q-tile, fastest per XCD
    const int gy   = xcd * (GY / 8) + (slot >> 4);  // sh slice, XCD-local
    const int m0   = gx * BMQ;
    const int n0   = gy * BNS;

    // S-DMA per-lane swizzled source offset (one call = 16 rows x 32 f16)
    const int rl = lane >> 2;
    const int qs = (lane & 3) ^ ((rl >> 1) & 3);
    const size_t srcoff = (size_t)rl * DIM + qs * 8;
    const f16* ps0 = sh + (size_t)(n0 + wid * 32) * DIM + srcoff;
    const f16* ps1 = ps0 + (size_t)16 * DIM;
    const int dS = wid * 1024;           // f16 offset of S row 32w in buffer

    // A-frag base: row m0 + wid*32 + l16, k-offset quad*8 (16B aligned)
    const f16* pA = xh + (size_t)(m0 + wid * 32 + l16) * DIM + quad * 8;

    f32x4 acc[2][8];
#pragma unroll
    for (int fi = 0; fi < 2; ++fi)
#pragma unroll
        for (int fj = 0; fj < 8; ++fj) acc[fi][fj] = (f32x4){0.f, 0.f, 0.f, 0.f};

    auto issueS = [&](int s) {
        f16* bs = &T[s % 3][dS];
        const int k0 = s * BK;
        gload16(ps0 + k0, bs);
        gload16(ps1 + k0, bs + 512);
    };

    // prologue: 2 S-stages in flight, FENCED so nothing hoists above them
    issueS(0);
    issueS(1);
    MEMFENCE;                 // pin S0,S1 as the oldest vmcnt entries

#pragma unroll
    for (int s = 0; s < NST; ++s) {
        MEMFENCE;             // pin A(s) after issueS(s+1) in the FIFO
        f16x8 A0 = *(const f16x8*)(pA +  0 * DIM + s * BK);
        f16x8 A1 = *(const f16x8*)(pA + 16 * DIM + s * BK);
        if (s < NST - 1)
            asm volatile("s_waitcnt vmcnt(4)\n\ts_barrier" ::: "memory");
        else
            asm volatile("s_waitcnt vmcnt(2)\n\ts_barrier" ::: "memory");
        if (s + 2 < NST) issueS(s + 2);

        const f16* TS = &T[s % 3][0];
#pragma unroll
        for (int fj = 0; fj < 8; ++fj) {
            f16x8 B = *fragp(TS, fj * 16 + l16, quad);
            acc[0][fj] = __builtin_amdgcn_mfma_f32_16x16x32_f16(A0, B, acc[0][fj], 0, 0, 0);
            acc[1][fj] = __builtin_amdgcn_mfma_f32_16x16x32_f16(A1, B, acc[1][fj], 0, 0, 0);
        }
    }

    // epilogue (R1-proven for 32q waves): per-slot top-2 over 8 cols,
    // 16-lane merge, write partials
    float s2v[8];
#pragma unroll
    for (int fj = 0; fj < 8; ++fj) s2v[fj] = s2g[n0 + fj * 16 + l16];
#pragma unroll
    for (int fi = 0; fi < 2; ++fi)
#pragma unroll
        for (int rg = 0; rg < 4; ++rg) {
            float bv1 = 3.4e38f, bv2 = 3.4e38f; int bi = 0;
#pragma unroll
            for (int fj = 0; fj < 8; ++fj) {
                float s = fmaf(-2.f, acc[fi][fj][rg], s2v[fj]);
                bv2 = fminf(bv2, fmaxf(bv1, s));
                bi  = (s < bv1) ? (n0 + fj * 16 + l16) : bi;
                bv1 = fminf(bv1, s);
            }
#pragma unroll
            for (int m = 1; m < 16; m <<= 1) {
                float ov1 = __shfl_xor(bv1, m);
                float ov2 = __shfl_xor(bv2, m);
                int   oi  = __shfl_xor(bi, m);
                float nb2 = fminf(fminf(bv2, ov2), fmaxf(bv1, ov1));
                bi  = (ov1 < bv1) ? oi : bi;
                bv1 = fminf(bv1, ov1);
                bv2 = nb2;
            }
            if (l16 == 0) {
                const int row = m0 + wid * 32 + fi * 16 + quad * 4 + rg;
                pv1[(size_t)row * GY + gy] = bv1;
                pv2[(size_t)row * GY + gy] = bv2;
                pi1[(size_t)row * GY + gy] = bi;
            }
        }
}

// ---------------------------------------------------------------------------
// Kernel 3 (R15-proven): FUSED finalize. One block per query, 128 threads:
//   phase 1 (wave 0): merge GY chunk-top2s -> (bv1, bv2, bi).
//   phase 2 (uniform branch): if bv2-bv1 <= EPS, exact fp32 rescan of
//     candidate chunks (pv1[c] <= bv1+EPS) inline (ascending-index
//     tie-break).
//   phase 3: label lookup + one-hot write.
// ---------------------------------------------------------------------------
__global__ __launch_bounds__(128) void finalize_fused(
    const float* __restrict__ pv1, const float* __restrict__ pv2,
    const int* __restrict__ pi1, const float* __restrict__ x,
    const float* __restrict__ sup, const float* __restrict__ s2,
    const int* __restrict__ labels, const int* __restrict__ ncp,
    int* __restrict__ out) {
    const int q = blockIdx.x, tid = threadIdx.x;
    const int lane = tid & 63, w = tid >> 6;      // 2 waves
    __shared__ float s_b1, s_b2;
    __shared__ int   s_bi;
    __shared__ float wv[2];
    __shared__ int   wi[2];
    __shared__ int   s_lbl;

    // phase 1: wave 0 merges the GY=256 chunk top-2 partials
    if (w == 0) {
        float bv1 = 3.4e38f, bv2 = 3.4e38f; int bi = 0;
        for (int t = lane; t < GY; t += 64) {
            float ov1 = pv1[(size_t)q * GY + t];
            float ov2 = pv2[(size_t)q * GY + t];
            int   oi  = pi1[(size_t)q * GY + t];
            float nb2 = fminf(fminf(bv2, ov2), fmaxf(bv1, ov1));
            bi  = (ov1 < bv1) ? oi : bi;
            bv1 = fminf(bv1, ov1);
            bv2 = nb2;
        }
#pragma unroll
        for (int m = 1; m < 64; m <<= 1) {
            float ov1 = __shfl_xor(bv1, m);
            float ov2 = __shfl_xor(bv2, m);
            int   oi  = __shfl_xor(bi, m);
            float nb2 = fminf(fminf(bv2, ov2), fmaxf(bv1, ov1));
            bi  = (ov1 < bv1) ? oi : bi;
            bv1 = fminf(bv1, ov1);
            bv2 = nb2;
        }
        if (lane == 0) { s_b1 = bv1; s_b2 = bv2; s_bi = bi; }
    }
    __syncthreads();
    int bi = s_bi;

    // phase 2: exact rescan for uncertified queries (block-uniform branch)
    if (s_b2 - s_b1 <= EPS) {
        const float qb = s_b1;
        const float4 xv = ((const float4*)(x + (size_t)q * DIM))[lane];
        float best = 3.4e38f; int bn = 0x7fffffff;
        for (int c = 0; c < GY; ++c) {
            if (pv1[(size_t)q * GY + c] > qb + EPS) continue;  // uniform skip
            const int base = c * BNS + w * 64;     // wave w: rows base..base+63
#pragma unroll 4
            for (int r = 0; r < 64; ++r) {
                const int n = base + r;
                float4 sv = ((const float4*)(sup + (size_t)n * DIM))[lane];
                float d = fmaf(sv.x, xv.x,
                          fmaf(sv.y, xv.y,
                          fmaf(sv.z, xv.z, sv.w * xv.w)));
#pragma unroll
                for (int m = 32; m > 0; m >>= 1) d += __shfl_xor(d, m);
                float sc = s2[n] - 2.f * d;
                if (sc < best) { best = sc; bn = n; }   // ascending n, strict <
            }
        }
        if (lane == 0) { wv[w] = best; wi[w] = bn; }
        __syncthreads();
        if (tid == 0) {
            float bv = wv[0]; int bx = wi[0];
            if (wv[1] < bv || (wv[1] == bv && wi[1] < bx)) { bx = wi[1]; }
            s_bi = bx;
        }
        __syncthreads();
        bi = s_bi;
    }

    // phase 3: label + one-hot
    if (tid == 0) {
        bool is64 = true;
        for (int i = 1; i < 128; i += 2)
            if (labels[i] != 0) { is64 = false; break; }
        s_lbl = is64 ? labels[2 * bi] : labels[bi];
    }
    __syncthreads();
    const int nc = ncp[0], lbl = s_lbl;
    for (int c = tid; c < nc; c += 128)
        out[q * nc + c] = (c == lbl) ? 1 : 0;
}

// ===========================================================================
// Slow path (ws too small): proven R3 fp32 kernels.
// ===========================================================================
#define SBM 128
#define SBN 128
#define SBK 16
#define SNT 4
#define SGY (NS / (SBN * SNT))
#define SLDT (SBM + 4)

__global__ __launch_bounds__(256) void s2_kernel(const float* __restrict__ s,
                                                 float* __restrict__ s2) {
    int wave = threadIdx.x >> 6, lane = threadIdx.x & 63;
    int row = blockIdx.x * 4 + wave;
    const float4* p = (const float4*)(s + (size_t)row * DIM);
    float4 v = p[lane];
    float sum = v.x * v.x + v.y * v.y + v.z * v.z + v.w * v.w;
#pragma unroll
    for (int off = 32; off > 0; off >>= 1) sum += __shfl_xor(sum, off);
    if (lane == 0) s2[row] = sum;
}

__global__ __launch_bounds__(256) void knn_f32(const float* __restrict__ x,
                                               const float* __restrict__ sup,
                                               const float* __restrict__ s2g,
                                               float* __restrict__ pvals,
                                               int* __restrict__ pidx) {
    __shared__ float Xs[SBK][SLDT];
    __shared__ float Bs[SBK][SLDT];
    const int tid = threadIdx.x;
    const int tx = tid & 15, ty = tid >> 4;
    const int m0 = blockIdx.x * SBM, by = blockIdx.y;
    const int srow = tid >> 2, skq = (tid & 3) * 4;
    float rmin[8]; int ridx[8];
#pragma unroll
    for (int i = 0; i < 8; ++i) { rmin[i] = 3.4e38f; ridx[i] = 0x7fffffff; }
    const float* xr0 = x + (size_t)(m0 + srow) * DIM + skq;
    const float* xr1 = x + (size_t)(m0 + 64 + srow) * DIM + skq;
    for (int nt = 0; nt < SNT; ++nt) {
        const int n0 = (by * SNT + nt) * SBN;
        const float* sr0 = sup + (size_t)(n0 + srow) * DIM + skq;
        const float* sr1 = sup + (size_t)(n0 + 64 + srow) * DIM + skq;
        float acc[8][8];
#pragma unroll
        for (int i = 0; i < 8; ++i)
#pragma unroll
            for (int j = 0; j < 8; ++j) acc[i][j] = 0.0f;
        for (int kt = 0; kt < DIM / SBK; ++kt) {
            const int k0 = kt * SBK;
            float4 xv0 = *(const float4*)(xr0 + k0);
            float4 xv1 = *(const float4*)(xr1 + k0);
            float4 sv0 = *(const float4*)(sr0 + k0);
            float4 sv1 = *(const float4*)(sr1 + k0);
            __syncthreads();
            Xs[skq + 0][srow] = xv0.x; Xs[skq + 1][srow] = xv0.y;
            Xs[skq + 2][srow] = xv0.z; Xs[skq + 3][srow] = xv0.w;
            Xs[skq + 0][64 + srow] = xv1.x; Xs[skq + 1][64 + srow] = xv1.y;
            Xs[skq + 2][64 + srow] = xv1.z; Xs[skq + 3][64 + srow] = xv1.w;
            Bs[skq + 0][srow] = sv0.x; Bs[skq + 1][srow] = sv0.y;
            Bs[skq + 2][srow] = sv0.z; Bs[skq + 3][srow] = sv0.w;
            Bs[skq + 0][64 + srow] = sv1.x; Bs[skq + 1][64 + srow] = sv1.y;
            Bs[skq + 2][64 + srow] = sv1.z; Bs[skq + 3][64 + srow] = sv1.w;
            __syncthreads();
#pragma unroll
            for (int k = 0; k < SBK; ++k) {
                float4 a0 = *(const float4*)&Xs[k][ty * 4];
                float4 a1 = *(const float4*)&Xs[k][64 + ty * 4];
                float4 b0 = *(const float4*)&Bs[k][tx * 4];
                float4 b1 = *(const float4*)&Bs[k][64 + tx * 4];
                float a[8] = {a0.x, a0.y, a0.z, a0.w, a1.x, a1.y, a1.z, a1.w};
                float b[8] = {b0.x, b0.y, b0.z, b0.w, b1.x, b1.y, b1.z, b1.w};
#pragma unroll
                for (int i = 0; i < 8; ++i)
#pragma unroll
                    for (int j = 0; j < 8; ++j)
                        acc[i][j] = fmaf(a[i], b[j], acc[i][j]);
            }
        }
        const int nb0 = n0 + tx * 4, nb1 = n0 + 64 + tx * 4;
        float4 s20 = *(const float4*)(s2g + nb0);
        float4 s21 = *(const float4*)(s2g + nb1);
        float s2a[8] = {s20.x, s20.y, s20.z, s20.w, s21.x, s21.y, s21.z, s21.w};
        int nca[8] = {nb0, nb0 + 1, nb0 + 2, nb0 + 3, nb1, nb1 + 1, nb1 + 2, nb1 + 3};
#pragma unroll
        for (int i = 0; i < 8; ++i)
#pragma unroll
            for (int j = 0; j < 8; ++j) {
                float sc = fmaf(-2.0f, acc[i][j], s2a[j]);
                if (sc < rmin[i] || (sc == rmin[i] && nca[j] < ridx[i])) {
                    rmin[i] = sc; ridx[i] = nca[j];
                }
            }
    }
    __syncthreads();
    float* redv = (float*)Xs;
    int* redi = (int*)Bs;
#pragma unroll
    for (int i = 0; i < 8; ++i) {
        int mrow = (i < 4) ? (ty * 4 + i) : (64 + ty * 4 + (i - 4));
        redv[mrow * 16 + tx] = rmin[i];
        redi[mrow * 16 + tx] = ridx[i];
    }
    __syncthreads();
    if (tid < SBM) {
        float best = redv[tid * 16];
        int bi = redi[tid * 16];
#pragma unroll
        for (int t = 1; t < 16; ++t) {
            float v = redv[tid * 16 + t];
            int ix = redi[tid * 16 + t];
            if (v < best || (v == best && ix < bi)) { best = v; bi = ix; }
        }
        pvals[(size_t)(m0 + tid) * SGY + by] = best;
        pidx[(size_t)(m0 + tid) * SGY + by] = bi;
    }
}

__global__ __launch_bounds__(64) void finalize_f32(const float* __restrict__ pvals,
                                                   const int* __restrict__ pidx,
                                                   const int* __restrict__ labels,
                                                   const int* __restrict__ ncp,
                                                   int* __restrict__ out) {
    const int b = blockIdx.x, lane = threadIdx.x;
    float v = pvals[(size_t)b * SGY + lane];
    int ix = pidx[(size_t)b * SGY + lane];
#pragma unroll
    for (int off = 32; off > 0; off >>= 1) {
        float ov = __shfl_xor(v, off);
        int oi = __shfl_xor(ix, off);
        if (ov < v || (ov == v && oi < ix)) { v = ov; ix = oi; }
    }
    bool is64 = true;
    for (int i = 1; i < 128; i += 2)
        if (labels[i] != 0) { is64 = false; break; }
    const int lbl = is64 ? labels[2 * ix] : labels[ix];
    const int nc = ncp[0];
    for (int c = lane; c < nc; c += 64)
        out[b * nc + c] = (c == lbl) ? 1 : 0;
}

// ---------------------------------------------------------------------------
extern "C" void kernel_launch(void* const* d_in, const int* in_sizes, int n_in,
                              void* d_out, int out_size, void* d_ws, size_t ws_size,
                              hipStream_t stream) {
    const float* x      = (const float*)d_in[0];
    const float* sup    = (const float*)d_in[1];
    const int*   labels = (const int*)d_in[2];
    const int*   ncp    = (const int*)d_in[3];
    int* out = (int*)d_out;

    // fast-path workspace layout (~23.4 MB)
    char* p = (char*)d_ws;
    float* s2      = (float*)p;           p += (size_t)NS * 4;
    float* pv1     = (float*)p;           p += (size_t)BQ * GY * 4;
    float* pv2     = (float*)p;           p += (size_t)BQ * GY * 4;
    int*   pi1     = (int*)p;             p += (size_t)BQ * GY * 4;
    f16*   xh      = (f16*)p;             p += (size_t)BQ * DIM * 2;   // row-major
    f16*   sh      = (f16*)p;             p += (size_t)NS * DIM * 2;   // row-major
    const size_t need = (size_t)(p - (char*)d_ws);

    if (ws_size >= need) {
        convert_kernel<<<NROWS / 4, 256, 0, stream>>>(x, sup, xh, sh, s2);
        dim3 grid(GX, GY);
        knn_mfma<<<grid, 256, 0, stream>>>(xh, sh, s2, pv1, pv2, pi1);
        finalize_fused<<<BQ, 128, 0, stream>>>(pv1, pv2, pi1, x, sup, s2,
                                               labels, ncp, out);
    } else {
        // slow path: proven fp32 pipeline (R3)
        float* ss2   = (float*)d_ws;
        float* pvals = ss2 + NS;
        int*   pidx  = (int*)(pvals + (size_t)BQ * SGY);
        s2_kernel<<<NS / 4, 256, 0, stream>>>(sup, ss2);
        dim3 sgrid(BQ / SBM, SGY);
        knn_f32<<<sgrid, 256, 0, stream>>>(x, sup, ss2, pvals, pidx);
        finalize_f32<<<BQ, 64, 0, stream>>>(pvals, pidx, labels, ncp, out);
    }
}

// Round 10
// 184.727 us; speedup vs baseline: 1.1080x; 1.0133x over previous
//
#include <hip/hip_runtime.h>

// ---------------------------------------------------------------------------
// Problem constants
#define BQ 2048
#define NS 32768
#define DIM 256
#define NROWS (NS + BQ)

// R20: block = 128q x 128s, 4 waves, wave = 32q x 128s; X in registers with
// ONE-STAGE A PREFETCH. R19 (no prefetch) exposed the A(s) load-to-use
// latency every stage: A issued at stage top, consumed right after the
// barrier -> ~200-500 cyc exposed x 8 stages. Measured: 616 cyc/stage vs
// 156 cyc MFMA issue = MfmaUtil 21%. Three structures (R1/R14/R19) all
// plateau at 60-66us sharing this post-barrier dependency pattern.
// A_cur/A_nxt double buffer gives A a full stage (~600 cyc) of lead.
#define BMQ 128                // queries per block
#define BNS 128                // supports per block
#define BK 32                  // K per stage
#define NST (DIM / BK)         // 8 pipeline stages
#define GY (NS / BNS)          // 256 chunks per query
#define GX (BQ / BMQ)          // 16 query tiles
// Certification: score = s2 - 2*(xh . sh), RTN f16. EPS = 0.08 ~ 8 sigma of
// per-pair error (validated: absmax 0 at R9-R16, R18, R19). Flagged queries
// get an exact candidate-chunk rescan inline.
#define EPS 0.08f

typedef _Float16 f16;
typedef _Float16 f16x4 __attribute__((ext_vector_type(4)));
typedef _Float16 f16x8 __attribute__((ext_vector_type(8)));
typedef float    f32x4 __attribute__((ext_vector_type(4)));

#define MEMFENCE asm volatile("" ::: "memory")

// ---------------------------------------------------------------------------
// global->LDS DMA, 16B/lane; LDS dest = wave-uniform base + lane*16.
// Per-lane source address carries the XOR swizzle (R7-verified: 0 conflicts).
// ---------------------------------------------------------------------------
__device__ __forceinline__ void gload16(const f16* g, f16* l) {
    __builtin_amdgcn_global_load_lds(
        (const __attribute__((address_space(1))) unsigned int*)g,
        (__attribute__((address_space(3))) unsigned int*)l, 16, 0, 0);
}

// Swizzled fragment pointer: rows of 32 f16 (64 B), cell q stored at
// q ^ ((row>>1)&3).  (S-side only since R17.)
__device__ __forceinline__ const f16x8* fragp(const f16* base, int row, int q) {
    return (const f16x8*)(base + row * 32 + ((q ^ ((row >> 1) & 3)) << 3));
}

// ---------------------------------------------------------------------------
// Kernel 1 (R4-proven): x -> f16 xh row-major, sup -> f16 sh row-major, s2
// exact fp32. One wave per row; contiguous 512B/wave writes.
// ---------------------------------------------------------------------------
__global__ __launch_bounds__(256) void convert_kernel(
    const float* __restrict__ x, const float* __restrict__ sup,
    f16* __restrict__ xh, f16* __restrict__ sh, float* __restrict__ s2) {
    const int wave = threadIdx.x >> 6, lane = threadIdx.x & 63;
    const int row = blockIdx.x * 4 + wave;
    if (row < NS) {
        float4 v = ((const float4*)(sup + (size_t)row * DIM))[lane];
        f16x4 hi;
        hi[0] = (f16)v.x; hi[1] = (f16)v.y; hi[2] = (f16)v.z; hi[3] = (f16)v.w;
        *(f16x4*)(sh + (size_t)row * DIM + lane * 4) = hi;
        float sum = v.x * v.x + v.y * v.y + v.z * v.z + v.w * v.w;
#pragma unroll
        for (int off = 32; off > 0; off >>= 1) sum += __shfl_xor(sum, off);
        if (lane == 0) s2[row] = sum;
    } else {
        const int q = row - NS;
        float4 v = ((const float4*)(x + (size_t)q * DIM))[lane];
        f16x4 hi;
        hi[0] = (f16)v.x; hi[1] = (f16)v.y; hi[2] = (f16)v.z; hi[3] = (f16)v.w;
        *(f16x4*)(xh + (size_t)q * DIM + lane * 4) = hi;
    }
}

// ---------------------------------------------------------------------------
// Kernel 2 (R20): f16 MFMA GEMM + top-2 argmin. 128x128 block tile,
// wave = 32q x 128s, X-in-registers with 1-stage A prefetch.
// VMEM linear order (MEMFENCE-pinned):  S0,S1,A0 | A1,W0,S2 | A2,W1,S3 | ...
// At W_s, younger-than-S(s) = {A(s):2, S(s+1):2, A(s+1):2} = 6 -> vmcnt(6)
// drains S(s); tail W_7: younger-than-S7 = {A7:2} -> vmcnt(2). A(s) has a
// full stage of lead; compiler's register-dep wait on A_cur is subsumed.
// R13 bijective XCD swizzle kept (FETCH 12.4 MB verified, R19).
// ---------------------------------------------------------------------------
__global__ __launch_bounds__(256, 3) void knn_mfma(
    const f16* __restrict__ xh, const f16* __restrict__ sh,
    const float* __restrict__ s2g,
    float* __restrict__ pv1, float* __restrict__ pv2, int* __restrict__ pi1) {
    __shared__ f16 T[3][BNS * 32];       // S triple-buffer, 24 KB

    const int tid  = threadIdx.x;
    const int lane = tid & 63, wid = tid >> 6;
    const int l16  = lane & 15, quad = lane >> 4;

    // R13 swizzle: id = y*GX+x; id%8 -> XCD; bijective (4096 = 8*512).
    const int id   = blockIdx.y * GX + blockIdx.x;
    const int xcd  = id & 7;
    const int slot = id >> 3;                 // 0..511
    const int gx   = slot & (GX - 1);         // q-tile, fastest per XCD
    const int gy   = xcd * (GY / 8) + (slot >> 4);  // sh slice, XCD-local
    const int m0   = gx * BMQ;
    const int n0   = gy * BNS;

    // S-DMA per-lane swizzled source offset (one call = 16 rows x 32 f16)
    const int rl = lane >> 2;
    const int qs = (lane & 3) ^ ((rl >> 1) & 3);
    const size_t srcoff = (size_t)rl * DIM + qs * 8;
    const f16* ps0 = sh + (size_t)(n0 + wid * 32) * DIM + srcoff;
    const f16* ps1 = ps0 + (size_t)16 * DIM;
    const int dS = wid * 1024;           // f16 offset of S row 32w in buffer

    // A-frag base: row m0 + wid*32 + l16, k-offset quad*8 (16B aligned)
    const f16* pA = xh + (size_t)(m0 + wid * 32 + l16) * DIM + quad * 8;

    f32x4 acc[2][8];
#pragma unroll
    for (int fi = 0; fi < 2; ++fi)
#pragma unroll
        for (int fj = 0; fj < 8; ++fj) acc[fi][fj] = (f32x4){0.f, 0.f, 0.f, 0.f};

    auto issueS = [&](int s) {
        f16* bs = &T[s % 3][dS];
        const int k0 = s * BK;
        gload16(ps0 + k0, bs);
        gload16(ps1 + k0, bs + 512);
    };

    // prologue: 2 S-stages in flight + A(0), order pinned
    issueS(0);
    issueS(1);
    MEMFENCE;                 // pin S0,S1 as the oldest vmcnt entries
    f16x8 A0c = *(const f16x8*)(pA +  0 * DIM);
    f16x8 A1c = *(const f16x8*)(pA + 16 * DIM);
    f16x8 A0n, A1n;

#pragma unroll
    for (int s = 0; s < NST; ++s) {
        MEMFENCE;             // pin A(s+1) after issueS(s+1) in the FIFO
        if (s + 1 < NST) {
            A0n = *(const f16x8*)(pA +  0 * DIM + (s + 1) * BK);
            A1n = *(const f16x8*)(pA + 16 * DIM + (s + 1) * BK);
        }
        if (s < NST - 1)
            asm volatile("s_waitcnt vmcnt(6)\n\ts_barrier" ::: "memory");
        else
            asm volatile("s_waitcnt vmcnt(2)\n\ts_barrier" ::: "memory");
        if (s + 2 < NST) issueS(s + 2);

        const f16* TS = &T[s % 3][0];
#pragma unroll
        for (int fj = 0; fj < 8; ++fj) {
            f16x8 B = *fragp(TS, fj * 16 + l16, quad);
            acc[0][fj] = __builtin_amdgcn_mfma_f32_16x16x32_f16(A0c, B, acc[0][fj], 0, 0, 0);
            acc[1][fj] = __builtin_amdgcn_mfma_f32_16x16x32_f16(A1c, B, acc[1][fj], 0, 0, 0);
        }
        A0c = A0n;
        A1c = A1n;
    }

    // epilogue (R1-proven for 32q waves): per-slot top-2 over 8 cols,
    // 16-lane merge, write partials
    float s2v[8];
#pragma unroll
    for (int fj = 0; fj < 8; ++fj) s2v[fj] = s2g[n0 + fj * 16 + l16];
#pragma unroll
    for (int fi = 0; fi < 2; ++fi)
#pragma unroll
        for (int rg = 0; rg < 4; ++rg) {
            float bv1 = 3.4e38f, bv2 = 3.4e38f; int bi = 0;
#pragma unroll
            for (int fj = 0; fj < 8; ++fj) {
                float s = fmaf(-2.f, acc[fi][fj][rg], s2v[fj]);
                bv2 = fminf(bv2, fmaxf(bv1, s));
                bi  = (s < bv1) ? (n0 + fj * 16 + l16) : bi;
                bv1 = fminf(bv1, s);
            }
#pragma unroll
            for (int m = 1; m < 16; m <<= 1) {
                float ov1 = __shfl_xor(bv1, m);
                float ov2 = __shfl_xor(bv2, m);
                int   oi  = __shfl_xor(bi, m);
                float nb2 = fminf(fminf(bv2, ov2), fmaxf(bv1, ov1));
                bi  = (ov1 < bv1) ? oi : bi;
                bv1 = fminf(bv1, ov1);
                bv2 = nb2;
            }
            if (l16 == 0) {
                const int row = m0 + wid * 32 + fi * 16 + quad * 4 + rg;
                pv1[(size_t)row * GY + gy] = bv1;
                pv2[(size_t)row * GY + gy] = bv2;
                pi1[(size_t)row * GY + gy] = bi;
            }
        }
}

// ---------------------------------------------------------------------------
// Kernel 3 (R20): FUSED finalize with LDS candidate flags. R9 evidence:
// fused non-knn ~121us vs unfused ~95 -- the rescan's per-chunk
// "load pv1[c]; branch" is a serial ~300cyc/iter latency chain (256 iters)
// in every flagged block. Fix: all 128 threads preload the 256 candidate
// flags coalesced into LDS, then the scan loop branches on LDS.
//   phase 1 (wave 0): merge GY chunk-top2s -> (bv1, bv2, bi).
//   phase 2 (uniform): if bv2-bv1 <= EPS, flags -> LDS, then exact fp32
//     rescan of candidate chunks (ascending-index tie-break).
//   phase 3: label lookup + one-hot write.
// ---------------------------------------------------------------------------
__global__ __launch_bounds__(128) void finalize_fused(
    const float* __restrict__ pv1, const float* __restrict__ pv2,
    const int* __restrict__ pi1, const float* __restrict__ x,
    const float* __restrict__ sup, const float* __restrict__ s2,
    const int* __restrict__ labels, const int* __restrict__ ncp,
    int* __restrict__ out) {
    const int q = blockIdx.x, tid = threadIdx.x;
    const int lane = tid & 63, w = tid >> 6;      // 2 waves
    __shared__ float s_b1, s_b2;
    __shared__ int   s_bi;
    __shared__ float wv[2];
    __shared__ int   wi[2];
    __shared__ int   s_lbl;
    __shared__ unsigned char cand[GY];

    // phase 1: wave 0 merges the GY=256 chunk top-2 partials
    if (w == 0) {
        float bv1 = 3.4e38f, bv2 = 3.4e38f; int bi = 0;
        for (int t = lane; t < GY; t += 64) {
            float ov1 = pv1[(size_t)q * GY + t];
            float ov2 = pv2[(size_t)q * GY + t];
            int   oi  = pi1[(size_t)q * GY + t];
            float nb2 = fminf(fminf(bv2, ov2), fmaxf(bv1, ov1));
            bi  = (ov1 < bv1) ? oi : bi;
            bv1 = fminf(bv1, ov1);
            bv2 = nb2;
        }
#pragma unroll
        for (int m = 1; m < 64; m <<= 1) {
            float ov1 = __shfl_xor(bv1, m);
            float ov2 = __shfl_xor(bv2, m);
            int   oi  = __shfl_xor(bi, m);
            float nb2 = fminf(fminf(bv2, ov2), fmaxf(bv1, ov1));
            bi  = (ov1 < bv1) ? oi : bi;
            bv1 = fminf(bv1, ov1);
            bv2 = nb2;
        }
        if (lane == 0) { s_b1 = bv1; s_b2 = bv2; s_bi = bi; }
    }
    __syncthreads();
    int bi = s_bi;

    // phase 2: exact rescan for uncertified queries (block-uniform branch)
    if (s_b2 - s_b1 <= EPS) {
        const float qb = s_b1;
        // cooperative coalesced flag preload (2 loads/thread)
        for (int c = tid; c < GY; c += 128)
            cand[c] = (pv1[(size_t)q * GY + c] <= qb + EPS) ? 1 : 0;
        __syncthreads();
        const float4 xv = ((const float4*)(x + (size_t)q * DIM))[lane];
        float best = 3.4e38f; int bn = 0x7fffffff;
        for (int c = 0; c < GY; ++c) {
            if (!cand[c]) continue;                // LDS branch, ~free
            const int base = c * BNS + w * 64;     // wave w: rows base..base+63
#pragma unroll 4
            for (int r = 0; r < 64; ++r) {
                const int n = base + r;
                float4 sv = ((const float4*)(sup + (size_t)n * DIM))[lane];
                float d = fmaf(sv.x, xv.x,
                          fmaf(sv.y, xv.y,
                          fmaf(sv.z, xv.z, sv.w * xv.w)));
#pragma unroll
                for (int m = 32; m > 0; m >>= 1) d += __shfl_xor(d, m);
                float sc = s2[n] - 2.f * d;
                if (sc < best) { best = sc; bn = n; }   // ascending n, strict <
            }
        }
        if (lane == 0) { wv[w] = best; wi[w] = bn; }
        __syncthreads();
        if (tid == 0) {
            float bv = wv[0]; int bx = wi[0];
            if (wv[1] < bv || (wv[1] == bv && wi[1] < bx)) { bx = wi[1]; }
            s_bi = bx;
        }
        __syncthreads();
        bi = s_bi;
    }

    // phase 3: label + one-hot
    if (tid == 0) {
        bool is64 = true;
        for (int i = 1; i < 128; i += 2)
            if (labels[i] != 0) { is64 = false; break; }
        s_lbl = is64 ? labels[2 * bi] : labels[bi];
    }
    __syncthreads();
    const int nc = ncp[0], lbl = s_lbl;
    for (int c = tid; c < nc; c += 128)
        out[q * nc + c] = (c == lbl) ? 1 : 0;
}

// ===========================================================================
// Slow path (ws too small): proven R3 fp32 kernels.
// ===========================================================================
#define SBM 128
#define SBN 128
#define SBK 16
#define SNT 4
#define SGY (NS / (SBN * SNT))
#define SLDT (SBM + 4)

__global__ __launch_bounds__(256) void s2_kernel(const float* __restrict__ s,
                                                 float* __restrict__ s2) {
    int wave = threadIdx.x >> 6, lane = threadIdx.x & 63;
    int row = blockIdx.x * 4 + wave;
    const float4* p = (const float4*)(s + (size_t)row * DIM);
    float4 v = p[lane];
    float sum = v.x * v.x + v.y * v.y + v.z * v.z + v.w * v.w;
#pragma unroll
    for (int off = 32; off > 0; off >>= 1) sum += __shfl_xor(sum, off);
    if (lane == 0) s2[row] = sum;
}

__global__ __launch_bounds__(256) void knn_f32(const float* __restrict__ x,
                                               const float* __restrict__ sup,
                                               const float* __restrict__ s2g,
                                               float* __restrict__ pvals,
                                               int* __restrict__ pidx) {
    __shared__ float Xs[SBK][SLDT];
    __shared__ float Bs[SBK][SLDT];
    const int tid = threadIdx.x;
    const int tx = tid & 15, ty = tid >> 4;
    const int m0 = blockIdx.x * SBM, by = blockIdx.y;
    const int srow = tid >> 2, skq = (tid & 3) * 4;
    float rmin[8]; int ridx[8];
#pragma unroll
    for (int i = 0; i < 8; ++i) { rmin[i] = 3.4e38f; ridx[i] = 0x7fffffff; }
    const float* xr0 = x + (size_t)(m0 + srow) * DIM + skq;
    const float* xr1 = x + (size_t)(m0 + 64 + srow) * DIM + skq;
    for (int nt = 0; nt < SNT; ++nt) {
        const int n0 = (by * SNT + nt) * SBN;
        const float* sr0 = sup + (size_t)(n0 + srow) * DIM + skq;
        const float* sr1 = sup + (size_t)(n0 + 64 + srow) * DIM + skq;
        float acc[8][8];
#pragma unroll
        for (int i = 0; i < 8; ++i)
#pragma unroll
            for (int j = 0; j < 8; ++j) acc[i][j] = 0.0f;
        for (int kt = 0; kt < DIM / SBK; ++kt) {
            const int k0 = kt * SBK;
            float4 xv0 = *(const float4*)(xr0 + k0);
            float4 xv1 = *(const float4*)(xr1 + k0);
            float4 sv0 = *(const float4*)(sr0 + k0);
            float4 sv1 = *(const float4*)(sr1 + k0);
            __syncthreads();
            Xs[skq + 0][srow] = xv0.x; Xs[skq + 1][srow] = xv0.y;
            Xs[skq + 2][srow] = xv0.z; Xs[skq + 3][srow] = xv0.w;
            Xs[skq + 0][64 + srow] = xv1.x; Xs[skq + 1][64 + srow] = xv1.y;
            Xs[skq + 2][64 + srow] = xv1.z; Xs[skq + 3][64 + srow] = xv1.w;
            Bs[skq + 0][srow] = sv0.x; Bs[skq + 1][srow] = sv0.y;
            Bs[skq + 2][srow] = sv0.z; Bs[skq + 3][srow] = sv0.w;
            Bs[skq + 0][64 + srow] = sv1.x; Bs[skq + 1][64 + srow] = sv1.y;
            Bs[skq + 2][64 + srow] = sv1.z; Bs[skq + 3][64 + srow] = sv1.w;
            __syncthreads();
#pragma unroll
            for (int k = 0; k < SBK; ++k) {
                float4 a0 = *(const float4*)&Xs[k][ty * 4];
                float4 a1 = *(const float4*)&Xs[k][64 + ty * 4];
                float4 b0 = *(const float4*)&Bs[k][tx * 4];
                float4 b1 = *(const float4*)&Bs[k][64 + tx * 4];
                float a[8] = {a0.x, a0.y, a0.z, a0.w, a1.x, a1.y, a1.z, a1.w};
                float b[8] = {b0.x, b0.y, b0.z, b0.w, b1.x, b1.y, b1.z, b1.w};
#pragma unroll
                for (int i = 0; i < 8; ++i)
#pragma unroll
                    for (int j = 0; j < 8; ++j)
                        acc[i][j] = fmaf(a[i], b[j], acc[i][j]);
            }
        }
        const int nb0 = n0 + tx * 4, nb1 = n0 + 64 + tx * 4;
        float4 s20 = *(const float4*)(s2g + nb0);
        float4 s21 = *(const float4*)(s2g + nb1);
        float s2a[8] = {s20.x, s20.y, s20.z, s20.w, s21.x, s21.y, s21.z, s21.w};
        int nca[8] = {nb0, nb0 + 1, nb0 + 2, nb0 + 3, nb1, nb1 + 1, nb1 + 2, nb1 + 3};
#pragma unroll
        for (int i = 0; i < 8; ++i)
#pragma unroll
            for (int j = 0; j < 8; ++j) {
                float sc = fmaf(-2.0f, acc[i][j], s2a[j]);
                if (sc < rmin[i] || (sc == rmin[i] && nca[j] < ridx[i])) {
                    rmin[i] = sc; ridx[i] = nca[j];
                }
            }
    }
    __syncthreads();
    float* redv = (float*)Xs;
    int* redi = (int*)Bs;
#pragma unroll
    for (int i = 0; i < 8; ++i) {
        int mrow = (i < 4) ? (ty * 4 + i) : (64 + ty * 4 + (i - 4));
        redv[mrow * 16 + tx] = rmin[i];
        redi[mrow * 16 + tx] = ridx[i];
    }
    __syncthreads();
    if (tid < SBM) {
        float best = redv[tid * 16];
        int bi = redi[tid * 16];
#pragma unroll
        for (int t = 1; t < 16; ++t) {
            float v = redv[tid * 16 + t];
            int ix = redi[tid * 16 + t];
            if (v < best || (v == best && ix < bi)) { best = v; bi = ix; }
        }
        pvals[(size_t)(m0 + tid) * SGY + by] = best;
        pidx[(size_t)(m0 + tid) * SGY + by] = bi;
    }
}

__global__ __launch_bounds__(64) void finalize_f32(const float* __restrict__ pvals,
                                                   const int* __restrict__ pidx,
                                                   const int* __restrict__ labels,
                                                   const int* __restrict__ ncp,
                                                   int* __restrict__ out) {
    const int b = blockIdx.x, lane = threadIdx.x;
    float v = pvals[(size_t)b * SGY + lane];
    int ix = pidx[(size_t)b * SGY + lane];
#pragma unroll
    for (int off = 32; off > 0; off >>= 1) {
        float ov = __shfl_xor(v, off);
        int oi = __shfl_xor(ix, off);
        if (ov < v || (ov == v && oi < ix)) { v = ov; ix = oi; }
    }
    bool is64 = true;
    for (int i = 1; i < 128; i += 2)
        if (labels[i] != 0) { is64 = false; break; }
    const int lbl = is64 ? labels[2 * ix] : labels[ix];
    const int nc = ncp[0];
    for (int c = lane; c < nc; c += 64)
        out[b * nc + c] = (c == lbl) ? 1 : 0;
}

// ---------------------------------------------------------------------------
extern "C" void kernel_launch(void* const* d_in, const int* in_sizes, int n_in,
                              void* d_out, int out_size, void* d_ws, size_t ws_size,
                              hipStream_t stream) {
    const float* x      = (const float*)d_in[0];
    const float* sup    = (const float*)d_in[1];
    const int*   labels = (const int*)d_in[2];
    const int*   ncp    = (const int*)d_in[3];
    int* out = (int*)d_out;

    // fast-path workspace layout (~23.4 MB)
    char* p = (char*)d_ws;
    float* s2      = (float*)p;           p += (size_t)NS * 4;
    float* pv1     = (float*)p;           p += (size_t)BQ * GY * 4;
    float* pv2     = (float*)p;           p += (size_t)BQ * GY * 4;
    int*   pi1     = (int*)p;             p += (size_t)BQ * GY * 4;
    f16*   xh      = (f16*)p;             p += (size_t)BQ * DIM * 2;   // row-major
    f16*   sh      = (f16*)p;             p += (size_t)NS * DIM * 2;   // row-major
    const size_t need = (size_t)(p - (char*)d_ws);

    if (ws_size >= need) {
        convert_kernel<<<NROWS / 4, 256, 0, stream>>>(x, sup, xh, sh, s2);
        dim3 grid(GX, GY);
        knn_mfma<<<grid, 256, 0, stream>>>(xh, sh, s2, pv1, pv2, pi1);
        finalize_fused<<<BQ, 128, 0, stream>>>(pv1, pv2, pi1, x, sup, s2,
                                               labels, ncp, out);
    } else {
        // slow path: proven fp32 pipeline (R3)
        float* ss2   = (float*)d_ws;
        float* pvals = ss2 + NS;
        int*   pidx  = (int*)(pvals + (size_t)BQ * SGY);
        s2_kernel<<<NS / 4, 256, 0, stream>>>(sup, ss2);
        dim3 sgrid(BQ / SBM, SGY);
        knn_f32<<<sgrid, 256, 0, stream>>>(x, sup, ss2, pvals, pidx);
        finalize_f32<<<BQ, 64, 0, stream>>>(pvals, pidx, labels, ncp, out);
    }
}

// Round 11
// 163.099 us; speedup vs baseline: 1.2549x; 1.1326x over previous
//
#include <hip/hip_runtime.h>

// ---------------------------------------------------------------------------
// Problem constants
#define BQ 2048
#define NS 32768
#define DIM 256
#define NROWS (NS + BQ)

// R21: BK=64 (4 stages). Evidence: five structures (R1/R14/R19/R20) all cap
// at 60-66us / MfmaUtil 19-23% == 540 TF == the documented 2-barrier-per-K-
// step family ceiling (m233: ~600 TF; per-stage overhead IS the critical
// path). Halving stage count halves that overhead per block; per-stage MFMA
// doubles (32). S tile 128x64 = 16KB x3 = 48KB LDS -> still 3 blocks/CU.
// X stays in registers (wave-private rows, R20-proven prefetch pattern).
#define BMQ 128                // queries per block
#define BNS 128                // supports per block
#define BK 64                  // K per stage
#define NST (DIM / BK)         // 4 pipeline stages
#define GY (NS / BNS)          // 256 chunks per query
#define GX (BQ / BMQ)          // 16 query tiles
// Certification: score = s2 - 2*(xh . sh), RTN f16. EPS = 0.08 ~ 8 sigma of
// per-pair error (validated: absmax 0 at R9-R16, R18-R20). Flagged queries
// go to the chunk-PARALLEL exact rescan (R21: reverted to the R3-proven
// 5-kernel pipeline -- the fused 1-block-per-query rescan was a tail-latency
// regression: (total-knn) 92-97 unfused vs 110-121 fused).
#define EPS 0.08f
#define FBCH GY                // fallback chunk granularity == partial chunks

typedef _Float16 f16;
typedef _Float16 f16x4 __attribute__((ext_vector_type(4)));
typedef _Float16 f16x8 __attribute__((ext_vector_type(8)));
typedef float    f32x4 __attribute__((ext_vector_type(4)));

#define MEMFENCE asm volatile("" ::: "memory")

// ---------------------------------------------------------------------------
// global->LDS DMA, 16B/lane; LDS dest = wave-uniform base + lane*16.
// Per-lane source address carries the XOR swizzle.
// ---------------------------------------------------------------------------
__device__ __forceinline__ void gload16(const f16* g, f16* l) {
    __builtin_amdgcn_global_load_lds(
        (const __attribute__((address_space(1))) unsigned int*)g,
        (__attribute__((address_space(3))) unsigned int*)l, 16, 0, 0);
}

// R21 B-fragment pointer for 64-f16 rows (128B): row r, 16B-cell c stored at
// cell c ^ (r&7). Read banks per 16-lane quad-group: (c^(r&7))*4 %32 -> 8
// banks x 2 lanes = 2-way (free, m136).
__device__ __forceinline__ const f16x8* fragB(const f16* base, int row, int cell) {
    return (const f16x8*)(base + row * 64 + ((cell ^ (row & 7)) << 3));
}

// ---------------------------------------------------------------------------
// Kernel 1 (R3-proven): x -> f16 xh, sup -> f16 sh, s2 exact fp32. One wave
// per row. Block 0 thread 0 zeroes fb_cnt.
// ---------------------------------------------------------------------------
__global__ __launch_bounds__(256) void convert_kernel(
    const float* __restrict__ x, const float* __restrict__ sup,
    f16* __restrict__ xh, f16* __restrict__ sh,
    float* __restrict__ s2, int* __restrict__ fb_cnt) {
    if (blockIdx.x == 0 && threadIdx.x == 0) *fb_cnt = 0;
    const int wave = threadIdx.x >> 6, lane = threadIdx.x & 63;
    const int row = blockIdx.x * 4 + wave;
    if (row < NS) {
        float4 v = ((const float4*)(sup + (size_t)row * DIM))[lane];
        f16x4 hi;
        hi[0] = (f16)v.x; hi[1] = (f16)v.y; hi[2] = (f16)v.z; hi[3] = (f16)v.w;
        *(f16x4*)(sh + (size_t)row * DIM + lane * 4) = hi;
        float sum = v.x * v.x + v.y * v.y + v.z * v.z + v.w * v.w;
#pragma unroll
        for (int off = 32; off > 0; off >>= 1) sum += __shfl_xor(sum, off);
        if (lane == 0) s2[row] = sum;
    } else {
        const int q = row - NS;
        float4 v = ((const float4*)(x + (size_t)q * DIM))[lane];
        f16x4 hi;
        hi[0] = (f16)v.x; hi[1] = (f16)v.y; hi[2] = (f16)v.z; hi[3] = (f16)v.w;
        *(f16x4*)(xh + (size_t)q * DIM + lane * 4) = hi;
    }
}

// ---------------------------------------------------------------------------
// Kernel 2 (R21): f16 MFMA GEMM + top-2 argmin. 128x128 block tile, BK=64,
// wave = 32q x 128s, X-in-registers with 1-stage A prefetch (R20-proven).
// VMEM linear order (MEMFENCE-pinned), 4 loads per issueS / 4 per A-stage:
//   S0,S1,A0 | A1,W0,S2 | A2,W1,S3 | A3,W2 | W3
// At W_s (s<3): issued-after-S(s) = {A(s),S(s+1),A(s+1)} or {A(s+1),S(s+2),
// A(s+2)} = 12 -> vmcnt(12) drains S(s). At W3: after-S3 = {A3} -> vmcnt(4).
// Compiler's mandatory A-register waits before MFMA only drain OLDER entries
// (in-order vmcnt retire) -- strictly safe (validated R18-R20, absmax 0).
// LDS: S rows of 64 f16, cell-XOR swizzle; DMA dest linear, source carries
// the swizzle: lane (rl8=lane>>3, cl=lane&7) reads source cell cl^rl8.
// R13 bijective XCD swizzle kept (FETCH 12.4 MB verified).
// ---------------------------------------------------------------------------
__global__ __launch_bounds__(256, 3) void knn_mfma(
    const f16* __restrict__ xh, const f16* __restrict__ sh,
    const float* __restrict__ s2g,
    float* __restrict__ pv1, float* __restrict__ pv2, int* __restrict__ pi1) {
    __shared__ f16 T[3][BNS * BK];       // S triple-buffer, 48 KB

    const int tid  = threadIdx.x;
    const int lane = tid & 63, wid = tid >> 6;
    const int l16  = lane & 15, quad = lane >> 4;

    // R13 swizzle: id = y*GX+x; id%8 -> XCD; bijective (4096 = 8*512).
    const int id   = blockIdx.y * GX + blockIdx.x;
    const int xcd  = id & 7;
    const int slot = id >> 3;                 // 0..511
    const int gx   = slot & (GX - 1);         // q-tile, fastest per XCD
    const int gy   = xcd * (GY / 8) + (slot >> 4);  // sh slice, XCD-local
    const int m0   = gx * BMQ;
    const int n0   = gy * BNS;

    // S-DMA per-lane swizzled source: 8-row groups, 16B cell = cl ^ rl8.
    const int rl8 = lane >> 3;           // row within 8-row group
    const int cl  = lane & 7;            // dest 16B cell
    const f16* psrc = sh + (size_t)(n0 + wid * 32 + rl8) * DIM + ((cl ^ rl8) << 3);
    const int dS = wid * 2048;           // f16 offset of S row 32w (row*64)

    // A-frag base: row m0 + wid*32 + l16, k-offset quad*8 (16B aligned)
    const f16* pA = xh + (size_t)(m0 + wid * 32 + l16) * DIM + quad * 8;

    f32x4 acc[2][8];
#pragma unroll
    for (int fi = 0; fi < 2; ++fi)
#pragma unroll
        for (int fj = 0; fj < 8; ++fj) acc[fi][fj] = (f32x4){0.f, 0.f, 0.f, 0.f};

    auto issueS = [&](int s) {
        f16* bs = &T[s % 3][dS];
        const f16* src = psrc + (size_t)s * BK;
        gload16(src,            bs);            // rows +0..7   -> 512 f16
        gload16(src +  8 * DIM, bs + 512);      // rows +8..15
        gload16(src + 16 * DIM, bs + 1024);     // rows +16..23
        gload16(src + 24 * DIM, bs + 1536);     // rows +24..31
    };

    // prologue: 2 S-stages in flight + A(0), order pinned
    issueS(0);
    issueS(1);
    MEMFENCE;                 // pin S0,S1 as the oldest vmcnt entries
    f16x8 A0c = *(const f16x8*)(pA);                  // row l16,    k-sub 0
    f16x8 A1c = *(const f16x8*)(pA + 32);             // row l16,    k-sub 1
    f16x8 A2c = *(const f16x8*)(pA + 16 * DIM);       // row l16+16, k-sub 0
    f16x8 A3c = *(const f16x8*)(pA + 16 * DIM + 32);  // row l16+16, k-sub 1

#pragma unroll
    for (int s = 0; s < NST; ++s) {
        MEMFENCE;             // pin A(s+1) after issueS(s+1) in the FIFO
        f16x8 A0n, A1n, A2n, A3n;
        if (s + 1 < NST) {
            const f16* pn = pA + (s + 1) * BK;
            A0n = *(const f16x8*)(pn);
            A1n = *(const f16x8*)(pn + 32);
            A2n = *(const f16x8*)(pn + 16 * DIM);
            A3n = *(const f16x8*)(pn + 16 * DIM + 32);
        }
        if (s < NST - 1)
            asm volatile("s_waitcnt vmcnt(12)\n\ts_barrier" ::: "memory");
        else
            asm volatile("s_waitcnt vmcnt(4)\n\ts_barrier" ::: "memory");
        if (s + 2 < NST) issueS(s + 2);

        const f16* TS = &T[s % 3][0];
#pragma unroll
        for (int fj = 0; fj < 8; ++fj) {
            f16x8 B0 = *fragB(TS, fj * 16 + l16, quad);       // k-sub 0
            acc[0][fj] = __builtin_amdgcn_mfma_f32_16x16x32_f16(A0c, B0, acc[0][fj], 0, 0, 0);
            acc[1][fj] = __builtin_amdgcn_mfma_f32_16x16x32_f16(A2c, B0, acc[1][fj], 0, 0, 0);
        }
#pragma unroll
        for (int fj = 0; fj < 8; ++fj) {
            f16x8 B1 = *fragB(TS, fj * 16 + l16, 4 + quad);   // k-sub 1
            acc[0][fj] = __builtin_amdgcn_mfma_f32_16x16x32_f16(A1c, B1, acc[0][fj], 0, 0, 0);
            acc[1][fj] = __builtin_amdgcn_mfma_f32_16x16x32_f16(A3c, B1, acc[1][fj], 0, 0, 0);
        }
        A0c = A0n; A1c = A1n; A2c = A2n; A3c = A3n;
    }

    // epilogue (R1-proven for 32q waves): per-slot top-2 over 8 cols,
    // 16-lane merge, write partials
    float s2v[8];
#pragma unroll
    for (int fj = 0; fj < 8; ++fj) s2v[fj] = s2g[n0 + fj * 16 + l16];
#pragma unroll
    for (int fi = 0; fi < 2; ++fi)
#pragma unroll
        for (int rg = 0; rg < 4; ++rg) {
            float bv1 = 3.4e38f, bv2 = 3.4e38f; int bi = 0;
#pragma unroll
            for (int fj = 0; fj < 8; ++fj) {
                float s = fmaf(-2.f, acc[fi][fj][rg], s2v[fj]);
                bv2 = fminf(bv2, fmaxf(bv1, s));
                bi  = (s < bv1) ? (n0 + fj * 16 + l16) : bi;
                bv1 = fminf(bv1, s);
            }
#pragma unroll
            for (int m = 1; m < 16; m <<= 1) {
                float ov1 = __shfl_xor(bv1, m);
                float ov2 = __shfl_xor(bv2, m);
                int   oi  = __shfl_xor(bi, m);
                float nb2 = fminf(fminf(bv2, ov2), fmaxf(bv1, ov1));
                bi  = (ov1 < bv1) ? oi : bi;
                bv1 = fminf(bv1, ov1);
                bv2 = nb2;
            }
            if (l16 == 0) {
                const int row = m0 + wid * 32 + fi * 16 + quad * 4 + rg;
                pv1[(size_t)row * GY + gy] = bv1;
                pv2[(size_t)row * GY + gy] = bv2;
                pi1[(size_t)row * GY + gy] = bi;
            }
        }
}

// ---------------------------------------------------------------------------
// Kernel 3 (R10-proven): merge GY chunk-top2s; one-hot; flag + list
// uncertified queries; store qbest for the candidate-chunk filter.
// ---------------------------------------------------------------------------
__global__ __launch_bounds__(128) void finalize2(
    const float* __restrict__ pv1, const float* __restrict__ pv2,
    const int* __restrict__ pi1, const int* __restrict__ labels,
    const int* __restrict__ ncp, int* __restrict__ out,
    int* __restrict__ fb_cnt, int* __restrict__ fb_list,
    float* __restrict__ qbest) {
    const int q = blockIdx.x, tid = threadIdx.x;
    __shared__ int s_label;
    if (tid < 64) {
        float bv1 = 3.4e38f, bv2 = 3.4e38f; int bi = 0;
        for (int t = tid; t < GY; t += 64) {
            float ov1 = pv1[(size_t)q * GY + t];
            float ov2 = pv2[(size_t)q * GY + t];
            int   oi  = pi1[(size_t)q * GY + t];
            float nb2 = fminf(fminf(bv2, ov2), fmaxf(bv1, ov1));
            bi  = (ov1 < bv1) ? oi : bi;
            bv1 = fminf(bv1, ov1);
            bv2 = nb2;
        }
#pragma unroll
        for (int m = 1; m < 64; m <<= 1) {
            float ov1 = __shfl_xor(bv1, m);
            float ov2 = __shfl_xor(bv2, m);
            int   oi  = __shfl_xor(bi, m);
            float nb2 = fminf(fminf(bv2, ov2), fmaxf(bv1, ov1));
            bi  = (ov1 < bv1) ? oi : bi;
            bv1 = fminf(bv1, ov1);
            bv2 = nb2;
        }
        if (tid == 0) {
            qbest[q] = bv1;
            if (bv2 - bv1 <= EPS) {
                int slot = atomicAdd(fb_cnt, 1);
                fb_list[slot] = q;
            }
            bool is64 = true;
            for (int i = 1; i < 128; i += 2)
                if (labels[i] != 0) { is64 = false; break; }
            s_label = is64 ? labels[2 * bi] : labels[bi];
        }
    }
    __syncthreads();
    const int nc = ncp[0], lbl = s_label;
    for (int c = tid; c < nc; c += 128)
        out[q * nc + c] = (c == lbl) ? 1 : 0;
}

// ---------------------------------------------------------------------------
// Kernel 4 (R10-proven): exact fp32 rescan for listed queries — candidate
// chunks only (pv1[q][c] <= qbest[q] + EPS). Skipped chunks write INF.
// Chunk-PARALLEL: grid (FBCH, 64) spreads each flagged query over 256 blocks.
// ---------------------------------------------------------------------------
__global__ __launch_bounds__(256) void fallback_scan(
    const float* __restrict__ x, const float* __restrict__ sup,
    const float* __restrict__ s2, const int* __restrict__ fb_cnt,
    const int* __restrict__ fb_list, const float* __restrict__ qbest,
    const float* __restrict__ pv1,
    float* __restrict__ fb_v, int* __restrict__ fb_i) {
    const int nslots = *fb_cnt;
    const int chunk = blockIdx.x;          // 0..FBCH-1, 128 rows each
    const int tid = threadIdx.x, lane = tid & 63, w = tid >> 6;
    __shared__ float wv[4];
    __shared__ int   wi[4];
    for (int slot = blockIdx.y; slot < nslots; slot += gridDim.y) {
        const int q = fb_list[slot];
        if (pv1[(size_t)q * GY + chunk] > qbest[q] + EPS) {
            if (tid == 0) {
                fb_v[(size_t)q * FBCH + chunk] = 3.4e38f;
                fb_i[(size_t)q * FBCH + chunk] = 0x7fffffff;
            }
            __syncthreads();
            continue;
        }
        const float4 xv = ((const float4*)(x + (size_t)q * DIM))[lane];
        float best = 3.4e38f; int bi = 0x7fffffff;
        const int base = chunk * BNS + w * 32;
#pragma unroll 4
        for (int r = 0; r < 32; ++r) {
            const int n = base + r;
            float4 sv = ((const float4*)(sup + (size_t)n * DIM))[lane];
            float d = fmaf(sv.x, xv.x,
                      fmaf(sv.y, xv.y,
                      fmaf(sv.z, xv.z, sv.w * xv.w)));
#pragma unroll
            for (int m = 32; m > 0; m >>= 1) d += __shfl_xor(d, m);
            float sc = s2[n] - 2.f * d;
            if (sc < best) { best = sc; bi = n; }   // ascending n, strict <
        }
        if (lane == 0) { wv[w] = best; wi[w] = bi; }
        __syncthreads();
        if (tid == 0) {
            float bv = wv[0]; int bx = wi[0];
#pragma unroll
            for (int t = 1; t < 4; ++t)
                if (wv[t] < bv || (wv[t] == bv && wi[t] < bx)) { bv = wv[t]; bx = wi[t]; }
            fb_v[(size_t)q * FBCH + chunk] = bv;
            fb_i[(size_t)q * FBCH + chunk] = bx;
        }
        __syncthreads();
    }
}

// ---------------------------------------------------------------------------
// Kernel 5 (R10-proven): merge FBCH partials, rewrite one-hot.
// ---------------------------------------------------------------------------
__global__ __launch_bounds__(64) void fallback_merge(
    const int* __restrict__ fb_cnt, const int* __restrict__ fb_list,
    const float* __restrict__ fb_v, const int* __restrict__ fb_i,
    const int* __restrict__ labels, const int* __restrict__ ncp,
    int* __restrict__ out) {
    const int nslots = *fb_cnt;
    const int lane = threadIdx.x;
    for (int slot = blockIdx.x; slot < nslots; slot += gridDim.x) {
        const int q = fb_list[slot];
        float v = 3.4e38f; int ix = 0x7fffffff;
        for (int t = lane; t < FBCH; t += 64) {
            float ov = fb_v[(size_t)q * FBCH + t];
            int   oi = fb_i[(size_t)q * FBCH + t];
            if (ov < v || (ov == v && oi < ix)) { v = ov; ix = oi; }
        }
#pragma unroll
        for (int m = 1; m < 64; m <<= 1) {
            float ov = __shfl_xor(v, m);
            int   oi = __shfl_xor(ix, m);
            if (ov < v || (ov == v && oi < ix)) { v = ov; ix = oi; }
        }
        bool is64 = true;
        for (int i = 1; i < 128; i += 2)
            if (labels[i] != 0) { is64 = false; break; }
        const int lbl = is64 ? labels[2 * ix] : labels[ix];
        const int nc = ncp[0];
        for (int c = lane; c < nc; c += 64)
            out[q * nc + c] = (c == lbl) ? 1 : 0;
    }
}

// ===========================================================================
// Slow path (ws too small): proven R3 fp32 kernels.
// ===========================================================================
#define SBM 128
#define SBN 128
#define SBK 16
#define SNT 4
#define SGY (NS / (SBN * SNT))
#define SLDT (SBM + 4)

__global__ __launch_bounds__(256) void s2_kernel(const float* __restrict__ s,
                                                 float* __restrict__ s2) {
    int wave = threadIdx.x >> 6, lane = threadIdx.x & 63;
    int row = blockIdx.x * 4 + wave;
    const float4* p = (const float4*)(s + (size_t)row * DIM);
    float4 v = p[lane];
    float sum = v.x * v.x + v.y * v.y + v.z * v.z + v.w * v.w;
#pragma unroll
    for (int off = 32; off > 0; off >>= 1) sum += __shfl_xor(sum, off);
    if (lane == 0) s2[row] = sum;
}

__global__ __launch_bounds__(256) void knn_f32(const float* __restrict__ x,
                                               const float* __restrict__ sup,
                                               const float* __restrict__ s2g,
                                               float* __restrict__ pvals,
                                               int* __restrict__ pidx) {
    __shared__ float Xs[SBK][SLDT];
    __shared__ float Bs[SBK][SLDT];
    const int tid = threadIdx.x;
    const int tx = tid & 15, ty = tid >> 4;
    const int m0 = blockIdx.x * SBM, by = blockIdx.y;
    const int srow = tid >> 2, skq = (tid & 3) * 4;
    float rmin[8]; int ridx[8];
#pragma unroll
    for (int i = 0; i < 8; ++i) { rmin[i] = 3.4e38f; ridx[i] = 0x7fffffff; }
    const float* xr0 = x + (size_t)(m0 + srow) * DIM + skq;
    const float* xr1 = x + (size_t)(m0 + 64 + srow) * DIM + skq;
    for (int nt = 0; nt < SNT; ++nt) {
        const int n0 = (by * SNT + nt) * SBN;
        const float* sr0 = sup + (size_t)(n0 + srow) * DIM + skq;
        const float* sr1 = sup + (size_t)(n0 + 64 + srow) * DIM + skq;
        float acc[8][8];
#pragma unroll
        for (int i = 0; i < 8; ++i)
#pragma unroll
            for (int j = 0; j < 8; ++j) acc[i][j] = 0.0f;
        for (int kt = 0; kt < DIM / SBK; ++kt) {
            const int k0 = kt * SBK;
            float4 xv0 = *(const float4*)(xr0 + k0);
            float4 xv1 = *(const float4*)(xr1 + k0);
            float4 sv0 = *(const float4*)(sr0 + k0);
            float4 sv1 = *(const float4*)(sr1 + k0);
            __syncthreads();
            Xs[skq + 0][srow] = xv0.x; Xs[skq + 1][srow] = xv0.y;
            Xs[skq + 2][srow] = xv0.z; Xs[skq + 3][srow] = xv0.w;
            Xs[skq + 0][64 + srow] = xv1.x; Xs[skq + 1][64 + srow] = xv1.y;
            Xs[skq + 2][64 + srow] = xv1.z; Xs[skq + 3][64 + srow] = xv1.w;
            Bs[skq + 0][srow] = sv0.x; Bs[skq + 1][srow] = sv0.y;
            Bs[skq + 2][srow] = sv0.z; Bs[skq + 3][srow] = sv0.w;
            Bs[skq + 0][64 + srow] = sv1.x; Bs[skq + 1][64 + srow] = sv1.y;
            Bs[skq + 2][64 + srow] = sv1.z; Bs[skq + 3][64 + srow] = sv1.w;
            __syncthreads();
#pragma unroll
            for (int k = 0; k < SBK; ++k) {
                float4 a0 = *(const float4*)&Xs[k][ty * 4];
                float4 a1 = *(const float4*)&Xs[k][64 + ty * 4];
                float4 b0 = *(const float4*)&Bs[k][tx * 4];
                float4 b1 = *(const float4*)&Bs[k][64 + tx * 4];
                float a[8] = {a0.x, a0.y, a0.z, a0.w, a1.x, a1.y, a1.z, a1.w};
                float b[8] = {b0.x, b0.y, b0.z, b0.w, b1.x, b1.y, b1.z, b1.w};
#pragma unroll
                for (int i = 0; i < 8; ++i)
#pragma unroll
                    for (int j = 0; j < 8; ++j)
                        acc[i][j] = fmaf(a[i], b[j], acc[i][j]);
            }
        }
        const int nb0 = n0 + tx * 4, nb1 = n0 + 64 + tx * 4;
        float4 s20 = *(const float4*)(s2g + nb0);
        float4 s21 = *(const float4*)(s2g + nb1);
        float s2a[8] = {s20.x, s20.y, s20.z, s20.w, s21.x, s21.y, s21.z, s21.w};
        int nca[8] = {nb0, nb0 + 1, nb0 + 2, nb0 + 3, nb1, nb1 + 1, nb1 + 2, nb1 + 3};
#pragma unroll
        for (int i = 0; i < 8; ++i)
#pragma unroll
            for (int j = 0; j < 8; ++j) {
                float sc = fmaf(-2.0f, acc[i][j], s2a[j]);
                if (sc < rmin[i] || (sc == rmin[i] && nca[j] < ridx[i])) {
                    rmin[i] = sc; ridx[i] = nca[j];
                }
            }
    }
    __syncthreads();
    float* redv = (float*)Xs;
    int* redi = (int*)Bs;
#pragma unroll
    for (int i = 0; i < 8; ++i) {
        int mrow = (i < 4) ? (ty * 4 + i) : (64 + ty * 4 + (i - 4));
        redv[mrow * 16 + tx] = rmin[i];
        redi[mrow * 16 + tx] = ridx[i];
    }
    __syncthreads();
    if (tid < SBM) {
        float best = redv[tid * 16];
        int bi = redi[tid * 16];
#pragma unroll
        for (int t = 1; t < 16; ++t) {
            float v = redv[tid * 16 + t];
            int ix = redi[tid * 16 + t];
            if (v < best || (v == best && ix < bi)) { best = v; bi = ix; }
        }
        pvals[(size_t)(m0 + tid) * SGY + by] = best;
        pidx[(size_t)(m0 + tid) * SGY + by] = bi;
    }
}

__global__ __launch_bounds__(64) void finalize_f32(const float* __restrict__ pvals,
                                                   const int* __restrict__ pidx,
                                                   const int* __restrict__ labels,
                                                   const int* __restrict__ ncp,
                                                   int* __restrict__ out) {
    const int b = blockIdx.x, lane = threadIdx.x;
    float v = pvals[(size_t)b * SGY + lane];
    int ix = pidx[(size_t)b * SGY + lane];
#pragma unroll
    for (int off = 32; off > 0; off >>= 1) {
        float ov = __shfl_xor(v, off);
        int oi = __shfl_xor(ix, off);
        if (ov < v || (ov == v && oi < ix)) { v = ov; ix = oi; }
    }
    bool is64 = true;
    for (int i = 1; i < 128; i += 2)
        if (labels[i] != 0) { is64 = false; break; }
    const int lbl = is64 ? labels[2 * ix] : labels[ix];
    const int nc = ncp[0];
    for (int c = lane; c < nc; c += 64)
        out[b * nc + c] = (c == lbl) ? 1 : 0;
}

// ---------------------------------------------------------------------------
extern "C" void kernel_launch(void* const* d_in, const int* in_sizes, int n_in,
                              void* d_out, int out_size, void* d_ws, size_t ws_size,
                              hipStream_t stream) {
    const float* x      = (const float*)d_in[0];
    const float* sup    = (const float*)d_in[1];
    const int*   labels = (const int*)d_in[2];
    const int*   ncp    = (const int*)d_in[3];
    int* out = (int*)d_out;

    // fast-path workspace layout (~27 MB)
    char* p = (char*)d_ws;
    float* s2      = (float*)p;           p += (size_t)NS * 4;
    float* pv1     = (float*)p;           p += (size_t)BQ * GY * 4;
    float* pv2     = (float*)p;           p += (size_t)BQ * GY * 4;
    int*   pi1     = (int*)p;             p += (size_t)BQ * GY * 4;
    int*   fb_cnt  = (int*)p;             p += 256;   // padded
    int*   fb_list = (int*)p;             p += (size_t)BQ * 4;
    float* qbest   = (float*)p;           p += (size_t)BQ * 4;
    float* fb_v    = (float*)p;           p += (size_t)BQ * FBCH * 4;
    int*   fb_i    = (int*)p;             p += (size_t)BQ * FBCH * 4;
    f16*   xh      = (f16*)p;             p += (size_t)BQ * DIM * 2;
    f16*   sh      = (f16*)p;             p += (size_t)NS * DIM * 2;
    const size_t need = (size_t)(p - (char*)d_ws);

    if (ws_size >= need) {
        convert_kernel<<<NROWS / 4, 256, 0, stream>>>(x, sup, xh, sh, s2, fb_cnt);
        dim3 grid(GX, GY);
        knn_mfma<<<grid, 256, 0, stream>>>(xh, sh, s2, pv1, pv2, pi1);
        finalize2<<<BQ, 128, 0, stream>>>(pv1, pv2, pi1, labels, ncp, out,
                                          fb_cnt, fb_list, qbest);
        dim3 fbgrid(FBCH, 64);
        fallback_scan<<<fbgrid, 256, 0, stream>>>(x, sup, s2, fb_cnt, fb_list,
                                                  qbest, pv1, fb_v, fb_i);
        fallback_merge<<<64, 64, 0, stream>>>(fb_cnt, fb_list, fb_v, fb_i, labels, ncp, out);
    } else {
        // slow path: proven fp32 pipeline (R3)
        float* ss2   = (float*)d_ws;
        float* pvals = ss2 + NS;
        int*   pidx  = (int*)(pvals + (size_t)BQ * SGY);
        s2_kernel<<<NS / 4, 256, 0, stream>>>(sup, ss2);
        dim3 sgrid(BQ / SBM, SGY);
        knn_f32<<<sgrid, 256, 0, stream>>>(x, sup, ss2, pvals, pidx);
        finalize_f32<<<BQ, 64, 0, stream>>>(pvals, pidx, labels, ncp, out);
    }
}